// Round 11
// baseline (226.555 us; speedup 1.0000x reference)
//
#include <hip/hip_runtime.h>
#include <hip/hip_bf16.h>

typedef __hip_bfloat16 bf16;

static constexpr int N_NODES = 100000;
static constexpr int N_EDGES = 3200000;
static constexpr int F_IN    = 54;
static constexpr int F_HID   = 16;

// bucket path
static constexpr int BSHIFT    = 7;                  // 128 nodes per bucket
static constexpr int BNODES    = 128;
static constexpr int NBUCK     = (N_NODES + BNODES - 1) / BNODES;  // 782
static constexpr int CAP_B     = 5120;
static constexpr int BIN_CHUNK = 4096;
static constexpr int BTHR      = 512;
static constexpr int EPT       = BIN_CHUNK / BTHR;   // 8 register-held edges
static constexpr int GRDB      = (N_EDGES + BIN_CHUNK - 1) / BIN_CHUNK;  // 782
static constexpr int GRDN_F    = (N_NODES + BTHR - 1) / BTHR;            // 196
static constexpr int HELD      = CAP_B / 512;        // 10 register-held edges per thread

// ---------------------------------------------------------------------------
// ws layout (float indices). hc1/hc2 are COMPACT 32-B rows:
// dword q = bf16(h[2q]) | bf16(h[2q+1])<<16  (8 dwords per node).
// a_src in separate fp32 tables (asrc1/asrc2) so the gather table fits the
// 4 MB per-XCD L2 (3.2 MB). agg1 persists its sorted CSR (srt->srcs,
// per-node cnt/beg) so agg2 skips the re-sort.
// ---------------------------------------------------------------------------
static constexpr size_t WS_FLAGS  = 0;        // 4 ints
static constexpr size_t WS_ADST   = 4;        // 100000
static constexpr size_t WS_ADST2  = 100004;   // 100000
static constexpr size_t WS_BCNT   = 200004;   // 1024 ints
static constexpr size_t WS_ASRC1  = 201028;   // 100000
static constexpr size_t WS_ASRC2  = 301028;   // 100000
static constexpr size_t WS_HC1    = 401028;   // 800,000 dw used
static constexpr size_t WS_RCNT   = 1201028;  // 100000 ints (HC1 region tail)
static constexpr size_t WS_RBEG   = 1301028;  // 100000 ints (HC1 region tail)
static constexpr size_t WS_HC2    = 2001028;  // 800,000 dw used (region 1.6M)
static constexpr size_t WS_BEDGES = 3601028;  // NBUCK*CAP_B ints
static constexpr size_t WS_SRCS   = 7604868;  // NBUCK*CAP_B ints (sorted CSR)
static constexpr size_t WS_BUCKET_END = WS_SRCS + (size_t)NBUCK * CAP_B; // 11,608,708
static constexpr size_t WS_FB_DEN     = 3601028;
static constexpr size_t WS_FB_AS      = 3701028;
static constexpr size_t WS_ATOMIC_END = 3801028;

__device__ __forceinline__ float lrelu(float v) { return fmaxf(v, 0.2f * v); }
__device__ __forceinline__ float loadf(const void* p, int i, bool f32) {
    return f32 ? ((const float*)p)[i] : __bfloat162float(((const bf16*)p)[i]);
}
__device__ __forceinline__ unsigned f2bf(float f) {   // RNE fp32->bf16 bits
    unsigned u = __float_as_uint(f);
    return (u + 0x7FFFu + ((u >> 16) & 1u)) >> 16;
}
__device__ __forceinline__ float bflo(unsigned u) { return __uint_as_float(u << 16); }
__device__ __forceinline__ float bfhi(unsigned u) { return __uint_as_float(u & 0xFFFF0000u); }

// ---------------------------------------------------------------------------
// Probe (+ zero bcnt): bit0 = floats fp32 ; bit1 = edge_index int64
// ---------------------------------------------------------------------------
__global__ __launch_bounds__(256) void k_probe0(
    const void* __restrict__ x, const void* __restrict__ ei,
    int* __restrict__ flags, int* __restrict__ bcnt)
{
    __shared__ int cnt, nz;
    const int t = threadIdx.x;
    if (t == 0) { cnt = 0; nz = 0; }
    __syncthreads();
    const unsigned u = ((const unsigned*)x)[t];
    if ((u & 0x7FFFu) >= 0x4800u) atomicAdd(&cnt, 1);
    if (t < 64) {
        if (((const unsigned*)ei)[2 * t + 1] != 0u) atomicAdd(&nz, 1);
    }
    for (int i = t; i < 1024; i += 256) bcnt[i] = 0;
    __syncthreads();
    if (t == 0) flags[0] = ((cnt >= 16) ? 1 : 0) | ((nz == 0) ? 2 : 0);
}

// ---------------------------------------------------------------------------
// k_binfeat (512 thr) — EXACT R5 (proven): [0,GRDB) bin with REGISTER-held
// edges, scalar loads; [GRDB,+GRDN_F) feat1: h1 = x@W1, emits compact 32-B
// row + fp32 asrc + fp32 adst.
// ---------------------------------------------------------------------------
__global__ __launch_bounds__(512, 8) void k_binfeat(
    const void* __restrict__ ei, const void* __restrict__ x,
    const void* __restrict__ W1, const void* __restrict__ a_s,
    const void* __restrict__ a_d, const int* __restrict__ flags,
    int* __restrict__ bcnt, int* __restrict__ bedges,
    unsigned* __restrict__ hc, float* __restrict__ asrc, float* __restrict__ adst)
{
    __shared__ int   hist[NBUCK];
    __shared__ int   base[NBUCK];
    __shared__ float Wl[F_IN * F_HID];
    __shared__ float asl[F_HID];
    __shared__ float adl[F_HID];
    const int t = threadIdx.x;
    const bool f32 = flags[0] & 1;
    const bool i64 = flags[0] & 2;

    if (blockIdx.x < GRDB) {
        const int e0 = blockIdx.x * BIN_CHUNK;
        const int valid = min(BIN_CHUNK, N_EDGES - e0);
        for (int i = t; i < NBUCK; i += BTHR) hist[i] = 0;
        __syncthreads();
        int cval_r[EPT];
        int bkt_r[EPT];
#pragma unroll
        for (int q = 0; q < EPT; ++q) {
            const int idx = q * BTHR + t;
            const int e = e0 + idx;
            bkt_r[q] = -1;
            if (idx < valid) {
                int s, d;
                if (i64) {
                    s = ((const int*)ei)[2 * (size_t)e];
                    d = ((const int*)ei)[2 * ((size_t)N_EDGES + e)];
                } else {
                    s = ((const int*)ei)[e];
                    d = ((const int*)ei)[(size_t)N_EDGES + e];
                }
                bkt_r[q] = d >> BSHIFT;
                cval_r[q] = (s << BSHIFT) | (d & (BNODES - 1));
                atomicAdd(&hist[bkt_r[q]], 1);
            }
        }
        __syncthreads();
        for (int i = t; i < NBUCK; i += BTHR) {
            const int c = hist[i];
            base[i] = c ? atomicAdd(&bcnt[i], c) : 0;
            hist[i] = 0;
        }
        __syncthreads();
#pragma unroll
        for (int q = 0; q < EPT; ++q) {
            if (bkt_r[q] >= 0) {
                const int b = bkt_r[q];
                const int r = atomicAdd(&hist[b], 1);
                const int pos = base[b] + r;
                if (pos < CAP_B) bedges[(size_t)b * CAP_B + pos] = cval_r[q];
            }
        }
    } else {
        for (int i = t; i < F_IN * F_HID; i += BTHR) Wl[i] = loadf(W1, i, f32);
        if (t < F_HID) { asl[t] = loadf(a_s, t, f32); adl[t] = loadf(a_d, t, f32); }
        __syncthreads();
        const int node = (blockIdx.x - GRDB) * BTHR + t;
        if (node >= N_NODES) return;

        float h[F_HID];
#pragma unroll
        for (int k = 0; k < F_HID; ++k) h[k] = 0.f;
        if (f32) {
            const float2* xp = (const float2*)((const float*)x + (size_t)node * F_IN);
#pragma unroll
            for (int j = 0; j < F_IN / 2; ++j) {
                const float2 v = xp[j];
#pragma unroll
                for (int k = 0; k < F_HID; ++k) {
                    h[k] = fmaf(v.x, Wl[(2*j)   * F_HID + k], h[k]);
                    h[k] = fmaf(v.y, Wl[(2*j+1) * F_HID + k], h[k]);
                }
            }
        } else {
            const unsigned* xu = (const unsigned*)x + (size_t)node * (F_IN / 2);
#pragma unroll
            for (int j = 0; j < F_IN / 2; ++j) {
                const unsigned u = xu[j];
                const float v0 = __uint_as_float(u << 16);
                const float v1 = __uint_as_float(u & 0xFFFF0000u);
#pragma unroll
                for (int k = 0; k < F_HID; ++k) {
                    h[k] = fmaf(v0, Wl[(2*j)   * F_HID + k], h[k]);
                    h[k] = fmaf(v1, Wl[(2*j+1) * F_HID + k], h[k]);
                }
            }
        }
        float s = 0.f, d = 0.f;
#pragma unroll
        for (int k = 0; k < F_HID; ++k) { s = fmaf(h[k], asl[k], s); d = fmaf(h[k], adl[k], d); }
        asrc[node] = s;
        adst[node] = d;
        unsigned pk[8];
#pragma unroll
        for (int q = 0; q < 8; ++q) pk[q] = f2bf(h[2*q]) | (f2bf(h[2*q+1]) << 16);
        uint4* hb = (uint4*)(hc + ((size_t)node << 3));
        hb[0] = make_uint4(pk[0], pk[1], pk[2], pk[3]);
        hb[1] = make_uint4(pk[4], pk[5], pk[6], pk[7]);
    }
}

// ---------------------------------------------------------------------------
// In-LDS bucket sort (proven R5): register-held edges, LDS hist+ladder scan.
// ---------------------------------------------------------------------------
__device__ __forceinline__ void bucket_sort_lds(
    const int* __restrict__ bedges, const int* __restrict__ bcnt, int b, int t,
    int* hist, int* scanv, int* cur, int* srt)
{
    if (t < BNODES) hist[t] = 0;
    __syncthreads();
    const int cnt = min(bcnt[b], CAP_B);
    const int* cv = bedges + (size_t)b * CAP_B;
    int held[HELD];
#pragma unroll
    for (int q = 0; q < HELD; ++q) {
        const int e = t + q * 512;                 // e <= 5119 < CAP_B: in-bounds
        const int v = cv[e];
        held[q] = (e < cnt) ? v : -1;
    }
#pragma unroll
    for (int q = 0; q < HELD; ++q)
        if (held[q] >= 0) atomicAdd(&hist[held[q] & (BNODES - 1)], 1);
    __syncthreads();
    if (t < BNODES) scanv[t] = hist[t];
    __syncthreads();
#pragma unroll
    for (int off = 1; off < BNODES; off <<= 1) {
        const int v = (t < BNODES && t >= off) ? scanv[t - off] : 0;
        __syncthreads();
        if (t < BNODES) scanv[t] += v;
        __syncthreads();
    }
    if (t < BNODES) cur[t] = scanv[t] - hist[t];
    __syncthreads();
#pragma unroll
    for (int q = 0; q < HELD; ++q) {
        if (held[q] >= 0) {
            const int p  = held[q];
            const int r  = atomicAdd(&cur[p & (BNODES - 1)], 1);
            srt[r] = p >> BSHIFT;
        }
    }
    __syncthreads();
}

// 12-deep gather+accumulate step (macro to keep both agg kernels identical)
#define GATHER12(HCP, ASP)                                                     \
    for (; i + 12 <= n; i += 12) {                                             \
        const int s0 = sp[i+0], s1 = sp[i+1], s2_ = sp[i+2], s3 = sp[i+3];     \
        const int s4 = sp[i+4], s5 = sp[i+5], s6 = sp[i+6], s7 = sp[i+7];      \
        const int s8 = sp[i+8], s9 = sp[i+9], sa_ = sp[i+10], sb_ = sp[i+11];  \
        const uint2 v0 = *(const uint2*)(HCP + ((size_t)s0 << 3) + (k2 << 1)); \
        const uint2 v1 = *(const uint2*)(HCP + ((size_t)s1 << 3) + (k2 << 1)); \
        const uint2 v2 = *(const uint2*)(HCP + ((size_t)s2_ << 3) + (k2 << 1));\
        const uint2 v3 = *(const uint2*)(HCP + ((size_t)s3 << 3) + (k2 << 1)); \
        const uint2 v4 = *(const uint2*)(HCP + ((size_t)s4 << 3) + (k2 << 1)); \
        const uint2 v5 = *(const uint2*)(HCP + ((size_t)s5 << 3) + (k2 << 1)); \
        const uint2 v6 = *(const uint2*)(HCP + ((size_t)s6 << 3) + (k2 << 1)); \
        const uint2 v7 = *(const uint2*)(HCP + ((size_t)s7 << 3) + (k2 << 1)); \
        const uint2 v8 = *(const uint2*)(HCP + ((size_t)s8 << 3) + (k2 << 1)); \
        const uint2 v9 = *(const uint2*)(HCP + ((size_t)s9 << 3) + (k2 << 1)); \
        const uint2 va = *(const uint2*)(HCP + ((size_t)sa_ << 3) + (k2 << 1));\
        const uint2 vb = *(const uint2*)(HCP + ((size_t)sb_ << 3) + (k2 << 1));\
        const float x0 = ASP[s0], x1 = ASP[s1], x2 = ASP[s2_], x3 = ASP[s3];   \
        const float x4 = ASP[s4], x5 = ASP[s5], x6 = ASP[s6], x7 = ASP[s7];    \
        const float x8 = ASP[s8], x9 = ASP[s9], xa = ASP[sa_], xb = ASP[sb_];  \
        const float e0 = __expf(lrelu(x0 + adn));                              \
        const float e1 = __expf(lrelu(x1 + adn));                              \
        const float e2 = __expf(lrelu(x2 + adn));                              \
        const float e3 = __expf(lrelu(x3 + adn));                              \
        const float e4 = __expf(lrelu(x4 + adn));                              \
        const float e5 = __expf(lrelu(x5 + adn));                              \
        const float e6 = __expf(lrelu(x6 + adn));                              \
        const float e7 = __expf(lrelu(x7 + adn));                              \
        const float e8 = __expf(lrelu(x8 + adn));                              \
        const float e9 = __expf(lrelu(x9 + adn));                              \
        const float ea = __expf(lrelu(xa + adn));                              \
        const float eb = __expf(lrelu(xb + adn));                              \
        denom += ((e0 + e1 + e2) + (e3 + e4 + e5)) +                           \
                 ((e6 + e7 + e8) + (e9 + ea + eb));                            \
        a0 = fmaf(e0, bflo(v0.x), a0); a1 = fmaf(e0, bfhi(v0.x), a1);          \
        a2 = fmaf(e0, bflo(v0.y), a2); a3 = fmaf(e0, bfhi(v0.y), a3);          \
        a0 = fmaf(e1, bflo(v1.x), a0); a1 = fmaf(e1, bfhi(v1.x), a1);          \
        a2 = fmaf(e1, bflo(v1.y), a2); a3 = fmaf(e1, bfhi(v1.y), a3);          \
        a0 = fmaf(e2, bflo(v2.x), a0); a1 = fmaf(e2, bfhi(v2.x), a1);          \
        a2 = fmaf(e2, bflo(v2.y), a2); a3 = fmaf(e2, bfhi(v2.y), a3);          \
        a0 = fmaf(e3, bflo(v3.x), a0); a1 = fmaf(e3, bfhi(v3.x), a1);          \
        a2 = fmaf(e3, bflo(v3.y), a2); a3 = fmaf(e3, bfhi(v3.y), a3);          \
        a0 = fmaf(e4, bflo(v4.x), a0); a1 = fmaf(e4, bfhi(v4.x), a1);          \
        a2 = fmaf(e4, bflo(v4.y), a2); a3 = fmaf(e4, bfhi(v4.y), a3);          \
        a0 = fmaf(e5, bflo(v5.x), a0); a1 = fmaf(e5, bfhi(v5.x), a1);          \
        a2 = fmaf(e5, bflo(v5.y), a2); a3 = fmaf(e5, bfhi(v5.y), a3);          \
        a0 = fmaf(e6, bflo(v6.x), a0); a1 = fmaf(e6, bfhi(v6.x), a1);          \
        a2 = fmaf(e6, bflo(v6.y), a2); a3 = fmaf(e6, bfhi(v6.y), a3);          \
        a0 = fmaf(e7, bflo(v7.x), a0); a1 = fmaf(e7, bfhi(v7.x), a1);          \
        a2 = fmaf(e7, bflo(v7.y), a2); a3 = fmaf(e7, bfhi(v7.y), a3);          \
        a0 = fmaf(e8, bflo(v8.x), a0); a1 = fmaf(e8, bfhi(v8.x), a1);          \
        a2 = fmaf(e8, bflo(v8.y), a2); a3 = fmaf(e8, bfhi(v8.y), a3);          \
        a0 = fmaf(e9, bflo(v9.x), a0); a1 = fmaf(e9, bfhi(v9.x), a1);          \
        a2 = fmaf(e9, bflo(v9.y), a2); a3 = fmaf(e9, bfhi(v9.y), a3);          \
        a0 = fmaf(ea, bflo(va.x), a0); a1 = fmaf(ea, bfhi(va.x), a1);          \
        a2 = fmaf(ea, bflo(va.y), a2); a3 = fmaf(ea, bfhi(va.y), a3);          \
        a0 = fmaf(eb, bflo(vb.x), a0); a1 = fmaf(eb, bfhi(vb.x), a1);          \
        a2 = fmaf(eb, bflo(vb.y), a2); a3 = fmaf(eb, bfhi(vb.y), a3);          \
    }                                                                          \
    for (; i + 4 <= n; i += 4) {                                               \
        const int s0 = sp[i+0], s1 = sp[i+1], s2_ = sp[i+2], s3 = sp[i+3];     \
        const uint2 v0 = *(const uint2*)(HCP + ((size_t)s0 << 3) + (k2 << 1)); \
        const uint2 v1 = *(const uint2*)(HCP + ((size_t)s1 << 3) + (k2 << 1)); \
        const uint2 v2 = *(const uint2*)(HCP + ((size_t)s2_ << 3) + (k2 << 1));\
        const uint2 v3 = *(const uint2*)(HCP + ((size_t)s3 << 3) + (k2 << 1)); \
        const float x0 = ASP[s0], x1 = ASP[s1], x2 = ASP[s2_], x3 = ASP[s3];   \
        const float e0 = __expf(lrelu(x0 + adn));                              \
        const float e1 = __expf(lrelu(x1 + adn));                              \
        const float e2 = __expf(lrelu(x2 + adn));                              \
        const float e3 = __expf(lrelu(x3 + adn));                              \
        denom += (e0 + e1) + (e2 + e3);                                        \
        a0 = fmaf(e0, bflo(v0.x), a0); a1 = fmaf(e0, bfhi(v0.x), a1);          \
        a2 = fmaf(e0, bflo(v0.y), a2); a3 = fmaf(e0, bfhi(v0.y), a3);          \
        a0 = fmaf(e1, bflo(v1.x), a0); a1 = fmaf(e1, bfhi(v1.x), a1);          \
        a2 = fmaf(e1, bflo(v1.y), a2); a3 = fmaf(e1, bfhi(v1.y), a3);          \
        a0 = fmaf(e2, bflo(v2.x), a0); a1 = fmaf(e2, bfhi(v2.x), a1);          \
        a2 = fmaf(e2, bflo(v2.y), a2); a3 = fmaf(e2, bfhi(v2.y), a3);          \
        a0 = fmaf(e3, bflo(v3.x), a0); a1 = fmaf(e3, bfhi(v3.x), a1);          \
        a2 = fmaf(e3, bflo(v3.y), a2); a3 = fmaf(e3, bfhi(v3.y), a3);          \
    }                                                                          \
    for (; i < n; ++i) {                                                       \
        const int s = sp[i];                                                   \
        const uint2 v = *(const uint2*)(HCP + ((size_t)s << 3) + (k2 << 1));   \
        const float w = __expf(lrelu(ASP[s] + adn));                           \
        denom += w;                                                            \
        a0 = fmaf(w, bflo(v.x), a0); a1 = fmaf(w, bfhi(v.x), a1);              \
        a2 = fmaf(w, bflo(v.y), a2); a3 = fmaf(w, bfhi(v.y), a3);              \
    }

// ---------------------------------------------------------------------------
// k_agg1: R10 structure + 12-deep gather pipeline (MLP 8->12; latency-bound
// per R10 counters: VALU 23%, HBM 11%). Persists sorted CSR for agg2.
// ---------------------------------------------------------------------------
__global__ __launch_bounds__(512, 6) void k_agg1(
    const int* __restrict__ bcnt, const int* __restrict__ bedges,
    const float* __restrict__ asrc, const float* __restrict__ adst,
    const unsigned* __restrict__ hc,
    const void* __restrict__ b1, const void* __restrict__ W2,
    const void* __restrict__ a_s2, const void* __restrict__ a_d2,
    const int* __restrict__ flags,
    unsigned* __restrict__ hc2, float* __restrict__ asrc2, float* __restrict__ adst2,
    int* __restrict__ srcs_g, int* __restrict__ rowcnt_g, int* __restrict__ rowbeg_g)
{
    __shared__ float Wl[F_HID * F_HID];
    __shared__ float asl[F_HID], adl[F_HID], bl[F_HID];
    __shared__ float adL[BNODES], asL[BNODES];
    __shared__ int hist[BNODES], scanv[BNODES], cur[BNODES];
    __shared__ int srt[CAP_B];
    const bool f32 = flags[0] & 1;
    const int t = threadIdx.x;
    const int b = blockIdx.x;
    const int n0 = b << BSHIFT;
    if (t < F_HID * F_HID) Wl[t] = loadf(W2, t, f32);
    if (t < F_HID) {
        asl[t] = loadf(a_s2, t, f32);
        adl[t] = loadf(a_d2, t, f32);
        bl[t]  = loadf(b1, t, f32);
    }
    if (t < BNODES) {
        const int node = n0 + t;
        const bool ok = node < N_NODES;
        adL[t] = ok ? adst[node] : 0.f;
        asL[t] = ok ? asrc[node] : 0.f;
    }
    bucket_sort_lds(bedges, bcnt, b, t, hist, scanv, cur, srt);

    // persist sorted CSR for k_agg2 (coalesced; no extra barriers needed)
    {
        const int cnt = min(bcnt[b], CAP_B);
        int* sg = srcs_g + (size_t)b * CAP_B;
        for (int i = t; i < cnt; i += 512) sg[i] = srt[i];
        if (t < BNODES) {
            const int node_ = n0 + t;
            if (node_ < N_NODES) {
                rowcnt_g[node_] = hist[t];
                rowbeg_g[node_] = scanv[t] - hist[t];   // bucket-local offset
            }
        }
    }

    const int k2 = t & 3;                 // lane in group: h comps 4*k2..4*k2+3
    const int g  = t >> 2;                // node-local 0..127
    const int node = n0 + g;
    if (node < N_NODES) {                 // group-uniform
        const int K = k2 << 2;
        const float adn = adL[g];
        // self-loop init
        const uint2 us = *(const uint2*)(hc + ((size_t)node << 3) + (k2 << 1));
        const float w0 = __expf(lrelu(asL[g] + adn));
        float denom = w0;
        float a0 = w0 * bflo(us.x), a1 = w0 * bfhi(us.x);
        float a2 = w0 * bflo(us.y), a3 = w0 * bfhi(us.y);
        const int n = hist[g];
        const int* sp = srt + (scanv[g] - n);
        int i = 0;
        GATHER12(hc, asrc)
        // epilogue: divide + bias + ELU
        const float inv = 1.f / denom;
        float z0 = a0 * inv + bl[K+0];
        float z1 = a1 * inv + bl[K+1];
        float z2 = a2 * inv + bl[K+2];
        float z3 = a3 * inv + bl[K+3];
        z0 = z0 > 0.f ? z0 : expm1f(z0);
        z1 = z1 > 0.f ? z1 : expm1f(z1);
        z2 = z2 > 0.f ? z2 : expm1f(z2);
        z3 = z3 > 0.f ? z3 : expm1f(z3);
        // z @ W2 via width-4 shuffles (each lane produces h2[K..K+3])
        float hh0 = 0.f, hh1 = 0.f, hh2 = 0.f, hh3 = 0.f;
#pragma unroll
        for (int jl = 0; jl < 4; ++jl) {
            const float zj0 = __shfl(z0, jl, 4);
            const float zj1 = __shfl(z1, jl, 4);
            const float zj2 = __shfl(z2, jl, 4);
            const float zj3 = __shfl(z3, jl, 4);
            const int jb = jl << 2;
            hh0 = fmaf(zj0, Wl[(jb+0)*F_HID + K+0], hh0);
            hh1 = fmaf(zj0, Wl[(jb+0)*F_HID + K+1], hh1);
            hh2 = fmaf(zj0, Wl[(jb+0)*F_HID + K+2], hh2);
            hh3 = fmaf(zj0, Wl[(jb+0)*F_HID + K+3], hh3);
            hh0 = fmaf(zj1, Wl[(jb+1)*F_HID + K+0], hh0);
            hh1 = fmaf(zj1, Wl[(jb+1)*F_HID + K+1], hh1);
            hh2 = fmaf(zj1, Wl[(jb+1)*F_HID + K+2], hh2);
            hh3 = fmaf(zj1, Wl[(jb+1)*F_HID + K+3], hh3);
            hh0 = fmaf(zj2, Wl[(jb+2)*F_HID + K+0], hh0);
            hh1 = fmaf(zj2, Wl[(jb+2)*F_HID + K+1], hh1);
            hh2 = fmaf(zj2, Wl[(jb+2)*F_HID + K+2], hh2);
            hh3 = fmaf(zj2, Wl[(jb+2)*F_HID + K+3], hh3);
            hh0 = fmaf(zj3, Wl[(jb+3)*F_HID + K+0], hh0);
            hh1 = fmaf(zj3, Wl[(jb+3)*F_HID + K+1], hh1);
            hh2 = fmaf(zj3, Wl[(jb+3)*F_HID + K+2], hh2);
            hh3 = fmaf(zj3, Wl[(jb+3)*F_HID + K+3], hh3);
        }
        float s2 = hh0*asl[K+0] + hh1*asl[K+1] + hh2*asl[K+2] + hh3*asl[K+3];
        float d2 = hh0*adl[K+0] + hh1*adl[K+1] + hh2*adl[K+2] + hh3*adl[K+3];
        s2 += __shfl_xor(s2, 1, 4); s2 += __shfl_xor(s2, 2, 4);
        d2 += __shfl_xor(d2, 1, 4); d2 += __shfl_xor(d2, 2, 4);
        uint2 w;
        w.x = f2bf(hh0) | (f2bf(hh1) << 16);
        w.y = f2bf(hh2) | (f2bf(hh3) << 16);
        *(uint2*)(hc2 + ((size_t)node << 3) + (k2 << 1)) = w;
        if (k2 == 0) { asrc2[node] = s2; adst2[node] = d2; }
    }
}

// ---------------------------------------------------------------------------
// k_agg2: NO re-sort — coalesced load of agg1's sorted CSR into LDS, then
// the 12-deep gather loop on layer-2 rows; writes fp32 out.
// ---------------------------------------------------------------------------
__global__ __launch_bounds__(512, 6) void k_agg2(
    const int* __restrict__ bcnt, const int* __restrict__ srcs_g,
    const int* __restrict__ rowcnt_g, const int* __restrict__ rowbeg_g,
    const float* __restrict__ asrc, const float* __restrict__ adst,
    const unsigned* __restrict__ hc,
    const void* __restrict__ b2, const int* __restrict__ flags,
    float* __restrict__ outp)
{
    __shared__ float bl[F_HID];
    __shared__ float adL[BNODES], asL[BNODES];
    __shared__ int histL[BNODES], begL[BNODES];
    __shared__ int srt[CAP_B];
    const bool f32 = flags[0] & 1;
    const int t = threadIdx.x;
    const int b = blockIdx.x;
    const int n0 = b << BSHIFT;
    if (t < F_HID) bl[t] = loadf(b2, t, f32);
    if (t < BNODES) {
        const int node_ = n0 + t;
        const bool ok = node_ < N_NODES;
        adL[t]  = ok ? adst[node_] : 0.f;
        asL[t]  = ok ? asrc[node_] : 0.f;
        histL[t] = ok ? rowcnt_g[node_] : 0;
        begL[t]  = ok ? rowbeg_g[node_] : 0;
    }
    const int cnt = min(bcnt[b], CAP_B);
    const int* sg = srcs_g + (size_t)b * CAP_B;
    for (int i = t; i < cnt; i += 512) srt[i] = sg[i];
    __syncthreads();

    const int k2 = t & 3;
    const int g  = t >> 2;
    const int node = n0 + g;
    if (node < N_NODES) {
        const int K = k2 << 2;
        const float adn = adL[g];
        const uint2 us = *(const uint2*)(hc + ((size_t)node << 3) + (k2 << 1));
        const float w0 = __expf(lrelu(asL[g] + adn));
        float denom = w0;
        float a0 = w0 * bflo(us.x), a1 = w0 * bfhi(us.x);
        float a2 = w0 * bflo(us.y), a3 = w0 * bfhi(us.y);
        const int n = histL[g];
        const int* sp = srt + begL[g];
        int i = 0;
        GATHER12(hc, asrc)
        const float inv = 1.f / denom;
        float4 o;
        o.x = a0 * inv + bl[K+0];
        o.y = a1 * inv + bl[K+1];
        o.z = a2 * inv + bl[K+2];
        o.w = a3 * inv + bl[K+3];
        *(float4*)(outp + ((size_t)node << 4) + K) = o;
    }
}

// ---------------------------------------------------------------------------
// Fallback kernels (round-3 proven atomic path, fp32 buffers) + diag
// ---------------------------------------------------------------------------
__global__ __launch_bounds__(256) void k_feat1(
    const void* __restrict__ x, const void* __restrict__ W1,
    const void* __restrict__ a_s, const void* __restrict__ a_d,
    const int* __restrict__ flags,
    float* __restrict__ hbuf, float* __restrict__ asrc, float* __restrict__ adst)
{
    const bool f32 = flags[0] & 1;
    __shared__ float Wl[F_IN * F_HID];
    __shared__ float asl[F_HID];
    __shared__ float adl[F_HID];
    const int t = threadIdx.x;
    for (int i = t; i < F_IN * F_HID; i += 256) Wl[i] = loadf(W1, i, f32);
    if (t < F_HID) { asl[t] = loadf(a_s, t, f32); adl[t] = loadf(a_d, t, f32); }
    __syncthreads();
    const int node = blockIdx.x * 256 + t;
    if (node >= N_NODES) return;
    float h[F_HID];
#pragma unroll
    for (int k = 0; k < F_HID; ++k) h[k] = 0.f;
    if (f32) {
        const float2* xp = (const float2*)((const float*)x + (size_t)node * F_IN);
#pragma unroll
        for (int j = 0; j < F_IN / 2; ++j) {
            const float2 v = xp[j];
#pragma unroll
            for (int k = 0; k < F_HID; ++k) {
                h[k] = fmaf(v.x, Wl[(2*j)   * F_HID + k], h[k]);
                h[k] = fmaf(v.y, Wl[(2*j+1) * F_HID + k], h[k]);
            }
        }
    } else {
        const unsigned* xu = (const unsigned*)x + (size_t)node * (F_IN / 2);
#pragma unroll
        for (int j = 0; j < F_IN / 2; ++j) {
            const unsigned u = xu[j];
            const float v0 = __uint_as_float(u << 16);
            const float v1 = __uint_as_float(u & 0xFFFF0000u);
#pragma unroll
            for (int k = 0; k < F_HID; ++k) {
                h[k] = fmaf(v0, Wl[(2*j)   * F_HID + k], h[k]);
                h[k] = fmaf(v1, Wl[(2*j+1) * F_HID + k], h[k]);
            }
        }
    }
    float s = 0.f, d = 0.f;
#pragma unroll
    for (int k = 0; k < F_HID; ++k) { s = fmaf(h[k], asl[k], s); d = fmaf(h[k], adl[k], d); }
    asrc[node] = s; adst[node] = d;
    float4* hb = (float4*)(hbuf + (size_t)node * F_HID);
#pragma unroll
    for (int q = 0; q < 4; ++q)
        hb[q] = make_float4(h[4*q], h[4*q+1], h[4*q+2], h[4*q+3]);
}

__global__ __launch_bounds__(256) void k_selfinit(
    const float* __restrict__ asrc, const float* __restrict__ adst,
    const float* __restrict__ h, float* __restrict__ denom, float* __restrict__ acc)
{
    const int t = blockIdx.x * 256 + threadIdx.x;
    if (t >= N_NODES * F_HID) return;
    const int n = t >> 4;
    const float w0 = __expf(lrelu(asrc[n] + adst[n]));
    if ((t & 15) == 0) denom[n] = w0;
    acc[t] = w0 * h[t];
}

__global__ __launch_bounds__(256) void k_edge(
    const void* __restrict__ ei, const int* __restrict__ flags,
    const float* __restrict__ asrc, const float* __restrict__ adst,
    const float* __restrict__ hbuf,
    float* __restrict__ denom, float* __restrict__ acc)
{
    const int e = blockIdx.x * 256 + threadIdx.x;
    if (e >= N_EDGES) return;
    int s, d;
    if (flags[0] & 2) {
        const long long* e64 = (const long long*)ei;
        s = (int)e64[e]; d = (int)e64[(size_t)N_EDGES + e];
    } else {
        const int* e32 = (const int*)ei;
        s = e32[e]; d = e32[(size_t)N_EDGES + e];
    }
    const float w = __expf(lrelu(asrc[s] + adst[d]));
    atomicAdd(&denom[d], w);
    const float4* hs = (const float4*)(hbuf + (size_t)s * F_HID);
    float* ad = acc + (size_t)d * F_HID;
#pragma unroll
    for (int q = 0; q < 4; ++q) {
        const float4 hv = hs[q];
        atomicAdd(ad + 4*q + 0, w * hv.x);
        atomicAdd(ad + 4*q + 1, w * hv.y);
        atomicAdd(ad + 4*q + 2, w * hv.z);
        atomicAdd(ad + 4*q + 3, w * hv.w);
    }
}

__global__ __launch_bounds__(256) void k_div_elu(
    float* __restrict__ acc, const float* __restrict__ denom,
    const void* __restrict__ b1, const int* __restrict__ flags)
{
    const bool f32 = flags[0] & 1;
    const int t = blockIdx.x * 256 + threadIdx.x;
    if (t >= N_NODES * F_HID) return;
    const float v = acc[t] / denom[t >> 4] + loadf(b1, t & 15, f32);
    acc[t] = v > 0.f ? v : expm1f(v);
}

__global__ __launch_bounds__(256) void k_mid(
    const float* __restrict__ z,
    const void* __restrict__ W2, const void* __restrict__ a_s2,
    const void* __restrict__ a_d2, const int* __restrict__ flags,
    float* __restrict__ h2, float* __restrict__ asrc, float* __restrict__ adst)
{
    const bool f32 = flags[0] & 1;
    __shared__ float Wl[F_HID * F_HID];
    __shared__ float asl[F_HID];
    __shared__ float adl[F_HID];
    const int t = threadIdx.x;
    if (t < F_HID * F_HID) Wl[t] = loadf(W2, t, f32);
    if (t < F_HID) { asl[t] = loadf(a_s2, t, f32); adl[t] = loadf(a_d2, t, f32); }
    __syncthreads();
    const int node = blockIdx.x * 256 + t;
    if (node >= N_NODES) return;
    float zr[F_HID];
    const float4* zi = (const float4*)(z + (size_t)node * F_HID);
#pragma unroll
    for (int q = 0; q < 4; ++q) {
        const float4 zv = zi[q];
        zr[4*q+0]=zv.x; zr[4*q+1]=zv.y; zr[4*q+2]=zv.z; zr[4*q+3]=zv.w;
    }
    float h[F_HID];
#pragma unroll
    for (int k = 0; k < F_HID; ++k) h[k] = 0.f;
#pragma unroll
    for (int j = 0; j < F_HID; ++j) {
        const float zv = zr[j];
#pragma unroll
        for (int k = 0; k < F_HID; ++k) h[k] = fmaf(zv, Wl[j * F_HID + k], h[k]);
    }
    float s = 0.f, d = 0.f;
#pragma unroll
    for (int k = 0; k < F_HID; ++k) { s = fmaf(h[k], asl[k], s); d = fmaf(h[k], adl[k], d); }
    asrc[node] = s; adst[node] = d;
    float4* hb = (float4*)(h2 + (size_t)node * F_HID);
#pragma unroll
    for (int q = 0; q < 4; ++q)
        hb[q] = make_float4(h[4*q], h[4*q+1], h[4*q+2], h[4*q+3]);
}

__global__ __launch_bounds__(256) void k_out(
    const float* __restrict__ acc, const float* __restrict__ denom,
    const void* __restrict__ b2, const int* __restrict__ flags,
    float* __restrict__ out)
{
    const bool f32 = flags[0] & 1;
    const int t = blockIdx.x * 256 + threadIdx.x;
    if (t >= N_NODES * F_HID) return;
    out[t] = acc[t] / denom[t >> 4] + loadf(b2, t & 15, f32);
}

__global__ __launch_bounds__(256) void k_diag(float* __restrict__ out, float v)
{
    const int t = blockIdx.x * 256 + threadIdx.x;
    if (t < N_NODES * F_HID) out[t] = v;
}

extern "C" void kernel_launch(void* const* d_in, const int* in_sizes, int n_in,
                              void* d_out, int out_size, void* d_ws, size_t ws_size,
                              hipStream_t stream) {
    const void* x   = d_in[0];
    const void* ei  = d_in[1];
    const void* W1  = d_in[2];
    const void* a1s = d_in[3];
    const void* a1d = d_in[4];
    const void* b1  = d_in[5];
    const void* W2  = d_in[6];
    const void* a2s = d_in[7];
    const void* a2d = d_in[8];
    const void* b2  = d_in[9];
    float* out = (float*)d_out;

    float* ws = (float*)d_ws;
    int*      flags  = (int*)(ws + WS_FLAGS);
    float*    adst   = ws + WS_ADST;
    float*    adst2  = ws + WS_ADST2;
    int*      bcnt   = (int*)(ws + WS_BCNT);
    float*    asrc1  = ws + WS_ASRC1;
    float*    asrc2  = ws + WS_ASRC2;
    unsigned* hc1    = (unsigned*)(ws + WS_HC1);
    unsigned* hc2    = (unsigned*)(ws + WS_HC2);
    int*      rowcnt = (int*)(ws + WS_RCNT);
    int*      rowbeg = (int*)(ws + WS_RBEG);
    int*      bedges = (int*)(ws + WS_BEDGES);
    int*      srcs   = (int*)(ws + WS_SRCS);

    const dim3 blk(256);
    const dim3 grdN((N_NODES + 255) / 256);
    const dim3 grdE((N_EDGES + 255) / 256);
    const dim3 grdO((N_NODES * F_HID + 255) / 256);
    const dim3 grdBF(GRDB + GRDN_F);
    const dim3 grdB(NBUCK);

    if (ws_size >= WS_BUCKET_END * 4) {
        k_probe0 <<<dim3(1), blk, 0, stream>>>(x, ei, flags, bcnt);
        k_binfeat<<<grdBF, dim3(BTHR), 0, stream>>>(ei, x, W1, a1s, a1d, flags,
                                                    bcnt, bedges, hc1, asrc1, adst);
        k_agg1   <<<grdB, dim3(512), 0, stream>>>(bcnt, bedges, asrc1, adst, hc1,
                                                  b1, W2, a2s, a2d, flags,
                                                  hc2, asrc2, adst2,
                                                  srcs, rowcnt, rowbeg);
        k_agg2   <<<grdB, dim3(512), 0, stream>>>(bcnt, srcs, rowcnt, rowbeg,
                                                  asrc2, adst2, hc2,
                                                  b2, flags, out);
    } else if (ws_size >= WS_ATOMIC_END * 4) {
        float* fb_h   = ws + WS_HC1;     // 1.6M fp32
        float* fb_acc = ws + WS_HC2;     // 1.6M fp32
        float* fb_den = ws + WS_FB_DEN;  // 100k
        float* fb_as  = ws + WS_FB_AS;   // 100k
        float* fb_ad  = ws + WS_ADST;
        k_probe0 <<<dim3(1), blk, 0, stream>>>(x, ei, flags, bcnt);
        k_feat1  <<<grdN, blk, 0, stream>>>(x, W1, a1s, a1d, flags, fb_h, fb_as, fb_ad);
        k_selfinit<<<grdO, blk, 0, stream>>>(fb_as, fb_ad, fb_h, fb_den, fb_acc);
        k_edge   <<<grdE, blk, 0, stream>>>(ei, flags, fb_as, fb_ad, fb_h, fb_den, fb_acc);
        k_div_elu<<<grdO, blk, 0, stream>>>(fb_acc, fb_den, b1, flags);
        k_mid    <<<grdN, blk, 0, stream>>>(fb_acc, W2, a2s, a2d, flags, fb_h, fb_as, fb_ad);
        k_selfinit<<<grdO, blk, 0, stream>>>(fb_as, fb_ad, fb_h, fb_den, fb_acc);
        k_edge   <<<grdE, blk, 0, stream>>>(ei, flags, fb_as, fb_ad, fb_h, fb_den, fb_acc);
        k_out    <<<grdO, blk, 0, stream>>>(fb_acc, fb_den, b2, flags, out);
    } else {
        k_diag<<<grdO, blk, 0, stream>>>(out, (float)(ws_size >> 10));
    }
}

// Round 12
// 220.108 us; speedup vs baseline: 1.0293x; 1.0293x over previous
//
#include <hip/hip_runtime.h>
#include <hip/hip_bf16.h>

typedef __hip_bfloat16 bf16;

static constexpr int N_NODES = 100000;
static constexpr int N_EDGES = 3200000;
static constexpr int F_IN    = 54;
static constexpr int F_HID   = 16;

// bucket path
static constexpr int BSHIFT    = 7;                  // 128 nodes per bucket
static constexpr int BNODES    = 128;
static constexpr int NBUCK     = (N_NODES + BNODES - 1) / BNODES;  // 782
static constexpr int CAP_B     = 5120;
static constexpr int BIN_CHUNK = 4096;
static constexpr int BTHR      = 512;
static constexpr int EPT       = BIN_CHUNK / BTHR;   // 8 register-held edges
static constexpr int GRDB      = (N_EDGES + BIN_CHUNK - 1) / BIN_CHUNK;  // 782
static constexpr int GRDN_F    = (N_NODES + BTHR - 1) / BTHR;            // 196
static constexpr int HELD      = CAP_B / 512;        // 10 register-held edges per thread

// ---------------------------------------------------------------------------
// ws layout (float indices). hc1/hc2 are COMPACT 32-B rows:
// dword q = bf16(h[2q]) | bf16(h[2q+1])<<16  (8 dwords per node).
// a_src in separate fp32 tables (asrc1/asrc2) so the gather table fits the
// 4 MB per-XCD L2 (3.2 MB). agg1 persists its sorted CSR (srt->srcs,
// per-node cnt/beg) so agg2 skips the re-sort and can use half-bucket blocks.
// ---------------------------------------------------------------------------
static constexpr size_t WS_FLAGS  = 0;        // 4 ints
static constexpr size_t WS_ADST   = 4;        // 100000
static constexpr size_t WS_ADST2  = 100004;   // 100000
static constexpr size_t WS_BCNT   = 200004;   // 1024 ints
static constexpr size_t WS_ASRC1  = 201028;   // 100000
static constexpr size_t WS_ASRC2  = 301028;   // 100000
static constexpr size_t WS_HC1    = 401028;   // 800,000 dw used
static constexpr size_t WS_RCNT   = 1201028;  // 100000 ints (HC1 region tail)
static constexpr size_t WS_RBEG   = 1301028;  // 100000 ints (HC1 region tail)
static constexpr size_t WS_HC2    = 2001028;  // 800,000 dw used (region 1.6M)
static constexpr size_t WS_BEDGES = 3601028;  // NBUCK*CAP_B ints
static constexpr size_t WS_SRCS   = 7604868;  // NBUCK*CAP_B ints (sorted CSR)
static constexpr size_t WS_BUCKET_END = WS_SRCS + (size_t)NBUCK * CAP_B; // 11,608,708
static constexpr size_t WS_FB_DEN     = 3601028;
static constexpr size_t WS_FB_AS      = 3701028;
static constexpr size_t WS_ATOMIC_END = 3801028;

__device__ __forceinline__ float lrelu(float v) { return fmaxf(v, 0.2f * v); }
__device__ __forceinline__ float loadf(const void* p, int i, bool f32) {
    return f32 ? ((const float*)p)[i] : __bfloat162float(((const bf16*)p)[i]);
}
__device__ __forceinline__ unsigned f2bf(float f) {   // RNE fp32->bf16 bits
    unsigned u = __float_as_uint(f);
    return (u + 0x7FFFu + ((u >> 16) & 1u)) >> 16;
}
__device__ __forceinline__ float bflo(unsigned u) { return __uint_as_float(u << 16); }
__device__ __forceinline__ float bfhi(unsigned u) { return __uint_as_float(u & 0xFFFF0000u); }

// ---------------------------------------------------------------------------
// Probe (+ zero bcnt): bit0 = floats fp32 ; bit1 = edge_index int64
// ---------------------------------------------------------------------------
__global__ __launch_bounds__(256) void k_probe0(
    const void* __restrict__ x, const void* __restrict__ ei,
    int* __restrict__ flags, int* __restrict__ bcnt)
{
    __shared__ int cnt, nz;
    const int t = threadIdx.x;
    if (t == 0) { cnt = 0; nz = 0; }
    __syncthreads();
    const unsigned u = ((const unsigned*)x)[t];
    if ((u & 0x7FFFu) >= 0x4800u) atomicAdd(&cnt, 1);
    if (t < 64) {
        if (((const unsigned*)ei)[2 * t + 1] != 0u) atomicAdd(&nz, 1);
    }
    for (int i = t; i < 1024; i += 256) bcnt[i] = 0;
    __syncthreads();
    if (t == 0) flags[0] = ((cnt >= 16) ? 1 : 0) | ((nz == 0) ? 2 : 0);
}

// ---------------------------------------------------------------------------
// k_binfeat (512 thr) — EXACT R5 (proven): [0,GRDB) bin with REGISTER-held
// edges, scalar loads; [GRDB,+GRDN_F) feat1: h1 = x@W1, emits compact 32-B
// row + fp32 asrc + fp32 adst.
// ---------------------------------------------------------------------------
__global__ __launch_bounds__(512, 8) void k_binfeat(
    const void* __restrict__ ei, const void* __restrict__ x,
    const void* __restrict__ W1, const void* __restrict__ a_s,
    const void* __restrict__ a_d, const int* __restrict__ flags,
    int* __restrict__ bcnt, int* __restrict__ bedges,
    unsigned* __restrict__ hc, float* __restrict__ asrc, float* __restrict__ adst)
{
    __shared__ int   hist[NBUCK];
    __shared__ int   base[NBUCK];
    __shared__ float Wl[F_IN * F_HID];
    __shared__ float asl[F_HID];
    __shared__ float adl[F_HID];
    const int t = threadIdx.x;
    const bool f32 = flags[0] & 1;
    const bool i64 = flags[0] & 2;

    if (blockIdx.x < GRDB) {
        const int e0 = blockIdx.x * BIN_CHUNK;
        const int valid = min(BIN_CHUNK, N_EDGES - e0);
        for (int i = t; i < NBUCK; i += BTHR) hist[i] = 0;
        __syncthreads();
        int cval_r[EPT];
        int bkt_r[EPT];
#pragma unroll
        for (int q = 0; q < EPT; ++q) {
            const int idx = q * BTHR + t;
            const int e = e0 + idx;
            bkt_r[q] = -1;
            if (idx < valid) {
                int s, d;
                if (i64) {
                    s = ((const int*)ei)[2 * (size_t)e];
                    d = ((const int*)ei)[2 * ((size_t)N_EDGES + e)];
                } else {
                    s = ((const int*)ei)[e];
                    d = ((const int*)ei)[(size_t)N_EDGES + e];
                }
                bkt_r[q] = d >> BSHIFT;
                cval_r[q] = (s << BSHIFT) | (d & (BNODES - 1));
                atomicAdd(&hist[bkt_r[q]], 1);
            }
        }
        __syncthreads();
        for (int i = t; i < NBUCK; i += BTHR) {
            const int c = hist[i];
            base[i] = c ? atomicAdd(&bcnt[i], c) : 0;
            hist[i] = 0;
        }
        __syncthreads();
#pragma unroll
        for (int q = 0; q < EPT; ++q) {
            if (bkt_r[q] >= 0) {
                const int b = bkt_r[q];
                const int r = atomicAdd(&hist[b], 1);
                const int pos = base[b] + r;
                if (pos < CAP_B) bedges[(size_t)b * CAP_B + pos] = cval_r[q];
            }
        }
    } else {
        for (int i = t; i < F_IN * F_HID; i += BTHR) Wl[i] = loadf(W1, i, f32);
        if (t < F_HID) { asl[t] = loadf(a_s, t, f32); adl[t] = loadf(a_d, t, f32); }
        __syncthreads();
        const int node = (blockIdx.x - GRDB) * BTHR + t;
        if (node >= N_NODES) return;

        float h[F_HID];
#pragma unroll
        for (int k = 0; k < F_HID; ++k) h[k] = 0.f;
        if (f32) {
            const float2* xp = (const float2*)((const float*)x + (size_t)node * F_IN);
#pragma unroll
            for (int j = 0; j < F_IN / 2; ++j) {
                const float2 v = xp[j];
#pragma unroll
                for (int k = 0; k < F_HID; ++k) {
                    h[k] = fmaf(v.x, Wl[(2*j)   * F_HID + k], h[k]);
                    h[k] = fmaf(v.y, Wl[(2*j+1) * F_HID + k], h[k]);
                }
            }
        } else {
            const unsigned* xu = (const unsigned*)x + (size_t)node * (F_IN / 2);
#pragma unroll
            for (int j = 0; j < F_IN / 2; ++j) {
                const unsigned u = xu[j];
                const float v0 = __uint_as_float(u << 16);
                const float v1 = __uint_as_float(u & 0xFFFF0000u);
#pragma unroll
                for (int k = 0; k < F_HID; ++k) {
                    h[k] = fmaf(v0, Wl[(2*j)   * F_HID + k], h[k]);
                    h[k] = fmaf(v1, Wl[(2*j+1) * F_HID + k], h[k]);
                }
            }
        }
        float s = 0.f, d = 0.f;
#pragma unroll
        for (int k = 0; k < F_HID; ++k) { s = fmaf(h[k], asl[k], s); d = fmaf(h[k], adl[k], d); }
        asrc[node] = s;
        adst[node] = d;
        unsigned pk[8];
#pragma unroll
        for (int q = 0; q < 8; ++q) pk[q] = f2bf(h[2*q]) | (f2bf(h[2*q+1]) << 16);
        uint4* hb = (uint4*)(hc + ((size_t)node << 3));
        hb[0] = make_uint4(pk[0], pk[1], pk[2], pk[3]);
        hb[1] = make_uint4(pk[4], pk[5], pk[6], pk[7]);
    }
}

// ---------------------------------------------------------------------------
// In-LDS bucket sort (proven R5): register-held edges, LDS hist+ladder scan.
// ---------------------------------------------------------------------------
__device__ __forceinline__ void bucket_sort_lds(
    const int* __restrict__ bedges, const int* __restrict__ bcnt, int b, int t,
    int* hist, int* scanv, int* cur, int* srt)
{
    if (t < BNODES) hist[t] = 0;
    __syncthreads();
    const int cnt = min(bcnt[b], CAP_B);
    const int* cv = bedges + (size_t)b * CAP_B;
    int held[HELD];
#pragma unroll
    for (int q = 0; q < HELD; ++q) {
        const int e = t + q * 512;                 // e <= 5119 < CAP_B: in-bounds
        const int v = cv[e];
        held[q] = (e < cnt) ? v : -1;
    }
#pragma unroll
    for (int q = 0; q < HELD; ++q)
        if (held[q] >= 0) atomicAdd(&hist[held[q] & (BNODES - 1)], 1);
    __syncthreads();
    if (t < BNODES) scanv[t] = hist[t];
    __syncthreads();
#pragma unroll
    for (int off = 1; off < BNODES; off <<= 1) {
        const int v = (t < BNODES && t >= off) ? scanv[t - off] : 0;
        __syncthreads();
        if (t < BNODES) scanv[t] += v;
        __syncthreads();
    }
    if (t < BNODES) cur[t] = scanv[t] - hist[t];
    __syncthreads();
#pragma unroll
    for (int q = 0; q < HELD; ++q) {
        if (held[q] >= 0) {
            const int p  = held[q];
            const int r  = atomicAdd(&cur[p & (BNODES - 1)], 1);
            srt[r] = p >> BSHIFT;
        }
    }
    __syncthreads();
}

// Proven 8-deep gather+accumulate (R10 loop; R11's 12-deep was a null/neg)
#define GATHER8(HCP, ASP)                                                      \
    for (; i + 8 <= n; i += 8) {                                               \
        const int s0 = sp[i+0], s1 = sp[i+1], s2_ = sp[i+2], s3 = sp[i+3];     \
        const int s4 = sp[i+4], s5 = sp[i+5], s6 = sp[i+6], s7 = sp[i+7];      \
        const uint2 v0 = *(const uint2*)(HCP + ((size_t)s0 << 3) + (k2 << 1)); \
        const uint2 v1 = *(const uint2*)(HCP + ((size_t)s1 << 3) + (k2 << 1)); \
        const uint2 v2 = *(const uint2*)(HCP + ((size_t)s2_ << 3) + (k2 << 1));\
        const uint2 v3 = *(const uint2*)(HCP + ((size_t)s3 << 3) + (k2 << 1)); \
        const uint2 v4 = *(const uint2*)(HCP + ((size_t)s4 << 3) + (k2 << 1)); \
        const uint2 v5 = *(const uint2*)(HCP + ((size_t)s5 << 3) + (k2 << 1)); \
        const uint2 v6 = *(const uint2*)(HCP + ((size_t)s6 << 3) + (k2 << 1)); \
        const uint2 v7 = *(const uint2*)(HCP + ((size_t)s7 << 3) + (k2 << 1)); \
        const float x0 = ASP[s0], x1 = ASP[s1], x2 = ASP[s2_], x3 = ASP[s3];   \
        const float x4 = ASP[s4], x5 = ASP[s5], x6 = ASP[s6], x7 = ASP[s7];    \
        const float e0 = __expf(lrelu(x0 + adn));                              \
        const float e1 = __expf(lrelu(x1 + adn));                              \
        const float e2 = __expf(lrelu(x2 + adn));                              \
        const float e3 = __expf(lrelu(x3 + adn));                              \
        const float e4 = __expf(lrelu(x4 + adn));                              \
        const float e5 = __expf(lrelu(x5 + adn));                              \
        const float e6 = __expf(lrelu(x6 + adn));                              \
        const float e7 = __expf(lrelu(x7 + adn));                              \
        denom += (e0 + e1 + e2 + e3) + (e4 + e5 + e6 + e7);                    \
        a0 = fmaf(e0, bflo(v0.x), a0); a1 = fmaf(e0, bfhi(v0.x), a1);          \
        a2 = fmaf(e0, bflo(v0.y), a2); a3 = fmaf(e0, bfhi(v0.y), a3);          \
        a0 = fmaf(e1, bflo(v1.x), a0); a1 = fmaf(e1, bfhi(v1.x), a1);          \
        a2 = fmaf(e1, bflo(v1.y), a2); a3 = fmaf(e1, bfhi(v1.y), a3);          \
        a0 = fmaf(e2, bflo(v2.x), a0); a1 = fmaf(e2, bfhi(v2.x), a1);          \
        a2 = fmaf(e2, bflo(v2.y), a2); a3 = fmaf(e2, bfhi(v2.y), a3);          \
        a0 = fmaf(e3, bflo(v3.x), a0); a1 = fmaf(e3, bfhi(v3.x), a1);          \
        a2 = fmaf(e3, bflo(v3.y), a2); a3 = fmaf(e3, bfhi(v3.y), a3);          \
        a0 = fmaf(e4, bflo(v4.x), a0); a1 = fmaf(e4, bfhi(v4.x), a1);          \
        a2 = fmaf(e4, bflo(v4.y), a2); a3 = fmaf(e4, bfhi(v4.y), a3);          \
        a0 = fmaf(e5, bflo(v5.x), a0); a1 = fmaf(e5, bfhi(v5.x), a1);          \
        a2 = fmaf(e5, bflo(v5.y), a2); a3 = fmaf(e5, bfhi(v5.y), a3);          \
        a0 = fmaf(e6, bflo(v6.x), a0); a1 = fmaf(e6, bfhi(v6.x), a1);          \
        a2 = fmaf(e6, bflo(v6.y), a2); a3 = fmaf(e6, bfhi(v6.y), a3);          \
        a0 = fmaf(e7, bflo(v7.x), a0); a1 = fmaf(e7, bfhi(v7.x), a1);          \
        a2 = fmaf(e7, bflo(v7.y), a2); a3 = fmaf(e7, bfhi(v7.y), a3);          \
    }                                                                          \
    for (; i < n; ++i) {                                                       \
        const int s = sp[i];                                                   \
        const uint2 v = *(const uint2*)(HCP + ((size_t)s << 3) + (k2 << 1));   \
        const float w = __expf(lrelu(ASP[s] + adn));                           \
        denom += w;                                                            \
        a0 = fmaf(w, bflo(v.x), a0); a1 = fmaf(w, bfhi(v.x), a1);              \
        a2 = fmaf(w, bflo(v.y), a2); a3 = fmaf(w, bfhi(v.y), a3);              \
    }

// ---------------------------------------------------------------------------
// k_agg1 (R10 proven, 8-deep): sort once, gather hc1/asrc1, ELU + z@W2,
// emit hc2/asrc2/adst2; persists sorted CSR for agg2.
// ---------------------------------------------------------------------------
__global__ __launch_bounds__(512, 6) void k_agg1(
    const int* __restrict__ bcnt, const int* __restrict__ bedges,
    const float* __restrict__ asrc, const float* __restrict__ adst,
    const unsigned* __restrict__ hc,
    const void* __restrict__ b1, const void* __restrict__ W2,
    const void* __restrict__ a_s2, const void* __restrict__ a_d2,
    const int* __restrict__ flags,
    unsigned* __restrict__ hc2, float* __restrict__ asrc2, float* __restrict__ adst2,
    int* __restrict__ srcs_g, int* __restrict__ rowcnt_g, int* __restrict__ rowbeg_g)
{
    __shared__ float Wl[F_HID * F_HID];
    __shared__ float asl[F_HID], adl[F_HID], bl[F_HID];
    __shared__ float adL[BNODES], asL[BNODES];
    __shared__ int hist[BNODES], scanv[BNODES], cur[BNODES];
    __shared__ int srt[CAP_B];
    const bool f32 = flags[0] & 1;
    const int t = threadIdx.x;
    const int b = blockIdx.x;
    const int n0 = b << BSHIFT;
    if (t < F_HID * F_HID) Wl[t] = loadf(W2, t, f32);
    if (t < F_HID) {
        asl[t] = loadf(a_s2, t, f32);
        adl[t] = loadf(a_d2, t, f32);
        bl[t]  = loadf(b1, t, f32);
    }
    if (t < BNODES) {
        const int node = n0 + t;
        const bool ok = node < N_NODES;
        adL[t] = ok ? adst[node] : 0.f;
        asL[t] = ok ? asrc[node] : 0.f;
    }
    bucket_sort_lds(bedges, bcnt, b, t, hist, scanv, cur, srt);

    // persist sorted CSR for k_agg2 (coalesced; no extra barriers needed)
    {
        const int cnt = min(bcnt[b], CAP_B);
        int* sg = srcs_g + (size_t)b * CAP_B;
        for (int i = t; i < cnt; i += 512) sg[i] = srt[i];
        if (t < BNODES) {
            const int node_ = n0 + t;
            if (node_ < N_NODES) {
                rowcnt_g[node_] = hist[t];
                rowbeg_g[node_] = scanv[t] - hist[t];   // bucket-local offset
            }
        }
    }

    const int k2 = t & 3;                 // lane in group: h comps 4*k2..4*k2+3
    const int g  = t >> 2;                // node-local 0..127
    const int node = n0 + g;
    if (node < N_NODES) {                 // group-uniform
        const int K = k2 << 2;
        const float adn = adL[g];
        // self-loop init
        const uint2 us = *(const uint2*)(hc + ((size_t)node << 3) + (k2 << 1));
        const float w0 = __expf(lrelu(asL[g] + adn));
        float denom = w0;
        float a0 = w0 * bflo(us.x), a1 = w0 * bfhi(us.x);
        float a2 = w0 * bflo(us.y), a3 = w0 * bfhi(us.y);
        const int n = hist[g];
        const int* sp = srt + (scanv[g] - n);
        int i = 0;
        GATHER8(hc, asrc)
        // epilogue: divide + bias + ELU
        const float inv = 1.f / denom;
        float z0 = a0 * inv + bl[K+0];
        float z1 = a1 * inv + bl[K+1];
        float z2 = a2 * inv + bl[K+2];
        float z3 = a3 * inv + bl[K+3];
        z0 = z0 > 0.f ? z0 : expm1f(z0);
        z1 = z1 > 0.f ? z1 : expm1f(z1);
        z2 = z2 > 0.f ? z2 : expm1f(z2);
        z3 = z3 > 0.f ? z3 : expm1f(z3);
        // z @ W2 via width-4 shuffles (each lane produces h2[K..K+3])
        float hh0 = 0.f, hh1 = 0.f, hh2 = 0.f, hh3 = 0.f;
#pragma unroll
        for (int jl = 0; jl < 4; ++jl) {
            const float zj0 = __shfl(z0, jl, 4);
            const float zj1 = __shfl(z1, jl, 4);
            const float zj2 = __shfl(z2, jl, 4);
            const float zj3 = __shfl(z3, jl, 4);
            const int jb = jl << 2;
            hh0 = fmaf(zj0, Wl[(jb+0)*F_HID + K+0], hh0);
            hh1 = fmaf(zj0, Wl[(jb+0)*F_HID + K+1], hh1);
            hh2 = fmaf(zj0, Wl[(jb+0)*F_HID + K+2], hh2);
            hh3 = fmaf(zj0, Wl[(jb+0)*F_HID + K+3], hh3);
            hh0 = fmaf(zj1, Wl[(jb+1)*F_HID + K+0], hh0);
            hh1 = fmaf(zj1, Wl[(jb+1)*F_HID + K+1], hh1);
            hh2 = fmaf(zj1, Wl[(jb+1)*F_HID + K+2], hh2);
            hh3 = fmaf(zj1, Wl[(jb+1)*F_HID + K+3], hh3);
            hh0 = fmaf(zj2, Wl[(jb+2)*F_HID + K+0], hh0);
            hh1 = fmaf(zj2, Wl[(jb+2)*F_HID + K+1], hh1);
            hh2 = fmaf(zj2, Wl[(jb+2)*F_HID + K+2], hh2);
            hh3 = fmaf(zj2, Wl[(jb+2)*F_HID + K+3], hh3);
            hh0 = fmaf(zj3, Wl[(jb+3)*F_HID + K+0], hh0);
            hh1 = fmaf(zj3, Wl[(jb+3)*F_HID + K+1], hh1);
            hh2 = fmaf(zj3, Wl[(jb+3)*F_HID + K+2], hh2);
            hh3 = fmaf(zj3, Wl[(jb+3)*F_HID + K+3], hh3);
        }
        float s2 = hh0*asl[K+0] + hh1*asl[K+1] + hh2*asl[K+2] + hh3*asl[K+3];
        float d2 = hh0*adl[K+0] + hh1*adl[K+1] + hh2*adl[K+2] + hh3*adl[K+3];
        s2 += __shfl_xor(s2, 1, 4); s2 += __shfl_xor(s2, 2, 4);
        d2 += __shfl_xor(d2, 1, 4); d2 += __shfl_xor(d2, 2, 4);
        uint2 w;
        w.x = f2bf(hh0) | (f2bf(hh1) << 16);
        w.y = f2bf(hh2) | (f2bf(hh3) << 16);
        *(uint2*)(hc2 + ((size_t)node << 3) + (k2 << 1)) = w;
        if (k2 == 0) { asrc2[node] = s2; adst2[node] = d2; }
    }
}

// ---------------------------------------------------------------------------
// k_agg2 (NEW shape): HALF-BUCKET blocks — 256 thr, 64 nodes each, grid
// 2*NBUCK = 1564. No sort (reads agg1's CSR); stages only its srt slice.
// ~21.5 KB LDS -> 7 blocks/CU capacity, ~6.1 avg residency (2x R11's 3.05)
// for latency hiding. Gather loop identical (8-deep).
// ---------------------------------------------------------------------------
__global__ __launch_bounds__(256, 8) void k_agg2(
    const int* __restrict__ bcnt, const int* __restrict__ srcs_g,
    const int* __restrict__ rowcnt_g, const int* __restrict__ rowbeg_g,
    const float* __restrict__ asrc, const float* __restrict__ adst,
    const unsigned* __restrict__ hc,
    const void* __restrict__ b2, const int* __restrict__ flags,
    float* __restrict__ outp)
{
    __shared__ float bl[F_HID];
    __shared__ float adL[64], asL[64];
    __shared__ int histL[64], begL[64];
    __shared__ int srtL[CAP_B];
    __shared__ int sh_beg0, sh_len;
    const bool f32 = flags[0] & 1;
    const int t = threadIdx.x;
    const int blk = blockIdx.x;
    const int b = blk >> 1;
    const int n0 = (b << BSHIFT) + ((blk & 1) << 6);   // first node of block
    if (t < F_HID) bl[t] = loadf(b2, t, f32);
    if (t < 64) {
        const int node_ = n0 + t;
        const bool ok = node_ < N_NODES;
        adL[t]  = ok ? adst[node_] : 0.f;
        asL[t]  = ok ? asrc[node_] : 0.f;
        histL[t] = ok ? rowcnt_g[node_] : 0;
        begL[t]  = ok ? rowbeg_g[node_] : 0;
    }
    __syncthreads();
    if (t == 0) {
        int beg0 = 0x7FFFFFFF, endv = 0;
        for (int g = 0; g < 64; ++g) {
            if (n0 + g < N_NODES) {
                beg0 = min(beg0, begL[g]);
                endv = max(endv, begL[g] + histL[g]);
            }
        }
        if (beg0 == 0x7FFFFFFF) { beg0 = 0; endv = 0; }
        sh_beg0 = beg0;
        sh_len  = endv - beg0;
    }
    __syncthreads();
    const int beg0 = sh_beg0;
    const int len  = sh_len;
    const int* sg = srcs_g + (size_t)b * CAP_B + beg0;
    for (int i = t; i < len; i += 256) srtL[i] = sg[i];
    __syncthreads();

    const int k2 = t & 3;
    const int g  = t >> 2;                 // 0..63
    const int node = n0 + g;
    if (node < N_NODES) {
        const int K = k2 << 2;
        const float adn = adL[g];
        const uint2 us = *(const uint2*)(hc + ((size_t)node << 3) + (k2 << 1));
        const float w0 = __expf(lrelu(asL[g] + adn));
        float denom = w0;
        float a0 = w0 * bflo(us.x), a1 = w0 * bfhi(us.x);
        float a2 = w0 * bflo(us.y), a3 = w0 * bfhi(us.y);
        const int n = histL[g];
        const int* sp = srtL + (begL[g] - beg0);
        int i = 0;
        GATHER8(hc, asrc)
        const float inv = 1.f / denom;
        float4 o;
        o.x = a0 * inv + bl[K+0];
        o.y = a1 * inv + bl[K+1];
        o.z = a2 * inv + bl[K+2];
        o.w = a3 * inv + bl[K+3];
        *(float4*)(outp + ((size_t)node << 4) + K) = o;
    }
}

// ---------------------------------------------------------------------------
// Fallback kernels (round-3 proven atomic path, fp32 buffers) + diag
// ---------------------------------------------------------------------------
__global__ __launch_bounds__(256) void k_feat1(
    const void* __restrict__ x, const void* __restrict__ W1,
    const void* __restrict__ a_s, const void* __restrict__ a_d,
    const int* __restrict__ flags,
    float* __restrict__ hbuf, float* __restrict__ asrc, float* __restrict__ adst)
{
    const bool f32 = flags[0] & 1;
    __shared__ float Wl[F_IN * F_HID];
    __shared__ float asl[F_HID];
    __shared__ float adl[F_HID];
    const int t = threadIdx.x;
    for (int i = t; i < F_IN * F_HID; i += 256) Wl[i] = loadf(W1, i, f32);
    if (t < F_HID) { asl[t] = loadf(a_s, t, f32); adl[t] = loadf(a_d, t, f32); }
    __syncthreads();
    const int node = blockIdx.x * 256 + t;
    if (node >= N_NODES) return;
    float h[F_HID];
#pragma unroll
    for (int k = 0; k < F_HID; ++k) h[k] = 0.f;
    if (f32) {
        const float2* xp = (const float2*)((const float*)x + (size_t)node * F_IN);
#pragma unroll
        for (int j = 0; j < F_IN / 2; ++j) {
            const float2 v = xp[j];
#pragma unroll
            for (int k = 0; k < F_HID; ++k) {
                h[k] = fmaf(v.x, Wl[(2*j)   * F_HID + k], h[k]);
                h[k] = fmaf(v.y, Wl[(2*j+1) * F_HID + k], h[k]);
            }
        }
    } else {
        const unsigned* xu = (const unsigned*)x + (size_t)node * (F_IN / 2);
#pragma unroll
        for (int j = 0; j < F_IN / 2; ++j) {
            const unsigned u = xu[j];
            const float v0 = __uint_as_float(u << 16);
            const float v1 = __uint_as_float(u & 0xFFFF0000u);
#pragma unroll
            for (int k = 0; k < F_HID; ++k) {
                h[k] = fmaf(v0, Wl[(2*j)   * F_HID + k], h[k]);
                h[k] = fmaf(v1, Wl[(2*j+1) * F_HID + k], h[k]);
            }
        }
    }
    float s = 0.f, d = 0.f;
#pragma unroll
    for (int k = 0; k < F_HID; ++k) { s = fmaf(h[k], asl[k], s); d = fmaf(h[k], adl[k], d); }
    asrc[node] = s; adst[node] = d;
    float4* hb = (float4*)(hbuf + (size_t)node * F_HID);
#pragma unroll
    for (int q = 0; q < 4; ++q)
        hb[q] = make_float4(h[4*q], h[4*q+1], h[4*q+2], h[4*q+3]);
}

__global__ __launch_bounds__(256) void k_selfinit(
    const float* __restrict__ asrc, const float* __restrict__ adst,
    const float* __restrict__ h, float* __restrict__ denom, float* __restrict__ acc)
{
    const int t = blockIdx.x * 256 + threadIdx.x;
    if (t >= N_NODES * F_HID) return;
    const int n = t >> 4;
    const float w0 = __expf(lrelu(asrc[n] + adst[n]));
    if ((t & 15) == 0) denom[n] = w0;
    acc[t] = w0 * h[t];
}

__global__ __launch_bounds__(256) void k_edge(
    const void* __restrict__ ei, const int* __restrict__ flags,
    const float* __restrict__ asrc, const float* __restrict__ adst,
    const float* __restrict__ hbuf,
    float* __restrict__ denom, float* __restrict__ acc)
{
    const int e = blockIdx.x * 256 + threadIdx.x;
    if (e >= N_EDGES) return;
    int s, d;
    if (flags[0] & 2) {
        const long long* e64 = (const long long*)ei;
        s = (int)e64[e]; d = (int)e64[(size_t)N_EDGES + e];
    } else {
        const int* e32 = (const int*)ei;
        s = e32[e]; d = e32[(size_t)N_EDGES + e];
    }
    const float w = __expf(lrelu(asrc[s] + adst[d]));
    atomicAdd(&denom[d], w);
    const float4* hs = (const float4*)(hbuf + (size_t)s * F_HID);
    float* ad = acc + (size_t)d * F_HID;
#pragma unroll
    for (int q = 0; q < 4; ++q) {
        const float4 hv = hs[q];
        atomicAdd(ad + 4*q + 0, w * hv.x);
        atomicAdd(ad + 4*q + 1, w * hv.y);
        atomicAdd(ad + 4*q + 2, w * hv.z);
        atomicAdd(ad + 4*q + 3, w * hv.w);
    }
}

__global__ __launch_bounds__(256) void k_div_elu(
    float* __restrict__ acc, const float* __restrict__ denom,
    const void* __restrict__ b1, const int* __restrict__ flags)
{
    const bool f32 = flags[0] & 1;
    const int t = blockIdx.x * 256 + threadIdx.x;
    if (t >= N_NODES * F_HID) return;
    const float v = acc[t] / denom[t >> 4] + loadf(b1, t & 15, f32);
    acc[t] = v > 0.f ? v : expm1f(v);
}

__global__ __launch_bounds__(256) void k_mid(
    const float* __restrict__ z,
    const void* __restrict__ W2, const void* __restrict__ a_s2,
    const void* __restrict__ a_d2, const int* __restrict__ flags,
    float* __restrict__ h2, float* __restrict__ asrc, float* __restrict__ adst)
{
    const bool f32 = flags[0] & 1;
    __shared__ float Wl[F_HID * F_HID];
    __shared__ float asl[F_HID];
    __shared__ float adl[F_HID];
    const int t = threadIdx.x;
    if (t < F_HID * F_HID) Wl[t] = loadf(W2, t, f32);
    if (t < F_HID) { asl[t] = loadf(a_s2, t, f32); adl[t] = loadf(a_d2, t, f32); }
    __syncthreads();
    const int node = blockIdx.x * 256 + t;
    if (node >= N_NODES) return;
    float zr[F_HID];
    const float4* zi = (const float4*)(z + (size_t)node * F_HID);
#pragma unroll
    for (int q = 0; q < 4; ++q) {
        const float4 zv = zi[q];
        zr[4*q+0]=zv.x; zr[4*q+1]=zv.y; zr[4*q+2]=zv.z; zr[4*q+3]=zv.w;
    }
    float h[F_HID];
#pragma unroll
    for (int k = 0; k < F_HID; ++k) h[k] = 0.f;
#pragma unroll
    for (int j = 0; j < F_HID; ++j) {
        const float zv = zr[j];
#pragma unroll
        for (int k = 0; k < F_HID; ++k) h[k] = fmaf(zv, Wl[j * F_HID + k], h[k]);
    }
    float s = 0.f, d = 0.f;
#pragma unroll
    for (int k = 0; k < F_HID; ++k) { s = fmaf(h[k], asl[k], s); d = fmaf(h[k], adl[k], d); }
    asrc[node] = s; adst[node] = d;
    float4* hb = (float4*)(h2 + (size_t)node * F_HID);
#pragma unroll
    for (int q = 0; q < 4; ++q)
        hb[q] = make_float4(h[4*q], h[4*q+1], h[4*q+2], h[4*q+3]);
}

__global__ __launch_bounds__(256) void k_out(
    const float* __restrict__ acc, const float* __restrict__ denom,
    const void* __restrict__ b2, const int* __restrict__ flags,
    float* __restrict__ out)
{
    const bool f32 = flags[0] & 1;
    const int t = blockIdx.x * 256 + threadIdx.x;
    if (t >= N_NODES * F_HID) return;
    out[t] = acc[t] / denom[t >> 4] + loadf(b2, t & 15, f32);
}

__global__ __launch_bounds__(256) void k_diag(float* __restrict__ out, float v)
{
    const int t = blockIdx.x * 256 + threadIdx.x;
    if (t < N_NODES * F_HID) out[t] = v;
}

extern "C" void kernel_launch(void* const* d_in, const int* in_sizes, int n_in,
                              void* d_out, int out_size, void* d_ws, size_t ws_size,
                              hipStream_t stream) {
    const void* x   = d_in[0];
    const void* ei  = d_in[1];
    const void* W1  = d_in[2];
    const void* a1s = d_in[3];
    const void* a1d = d_in[4];
    const void* b1  = d_in[5];
    const void* W2  = d_in[6];
    const void* a2s = d_in[7];
    const void* a2d = d_in[8];
    const void* b2  = d_in[9];
    float* out = (float*)d_out;

    float* ws = (float*)d_ws;
    int*      flags  = (int*)(ws + WS_FLAGS);
    float*    adst   = ws + WS_ADST;
    float*    adst2  = ws + WS_ADST2;
    int*      bcnt   = (int*)(ws + WS_BCNT);
    float*    asrc1  = ws + WS_ASRC1;
    float*    asrc2  = ws + WS_ASRC2;
    unsigned* hc1    = (unsigned*)(ws + WS_HC1);
    unsigned* hc2    = (unsigned*)(ws + WS_HC2);
    int*      rowcnt = (int*)(ws + WS_RCNT);
    int*      rowbeg = (int*)(ws + WS_RBEG);
    int*      bedges = (int*)(ws + WS_BEDGES);
    int*      srcs   = (int*)(ws + WS_SRCS);

    const dim3 blk(256);
    const dim3 grdN((N_NODES + 255) / 256);
    const dim3 grdE((N_EDGES + 255) / 256);
    const dim3 grdO((N_NODES * F_HID + 255) / 256);
    const dim3 grdBF(GRDB + GRDN_F);
    const dim3 grdB(NBUCK);
    const dim3 grdB2(NBUCK * 2);

    if (ws_size >= WS_BUCKET_END * 4) {
        k_probe0 <<<dim3(1), blk, 0, stream>>>(x, ei, flags, bcnt);
        k_binfeat<<<grdBF, dim3(BTHR), 0, stream>>>(ei, x, W1, a1s, a1d, flags,
                                                    bcnt, bedges, hc1, asrc1, adst);
        k_agg1   <<<grdB, dim3(512), 0, stream>>>(bcnt, bedges, asrc1, adst, hc1,
                                                  b1, W2, a2s, a2d, flags,
                                                  hc2, asrc2, adst2,
                                                  srcs, rowcnt, rowbeg);
        k_agg2   <<<grdB2, dim3(256), 0, stream>>>(bcnt, srcs, rowcnt, rowbeg,
                                                   asrc2, adst2, hc2,
                                                   b2, flags, out);
    } else if (ws_size >= WS_ATOMIC_END * 4) {
        float* fb_h   = ws + WS_HC1;     // 1.6M fp32
        float* fb_acc = ws + WS_HC2;     // 1.6M fp32
        float* fb_den = ws + WS_FB_DEN;  // 100k
        float* fb_as  = ws + WS_FB_AS;   // 100k
        float* fb_ad  = ws + WS_ADST;
        k_probe0 <<<dim3(1), blk, 0, stream>>>(x, ei, flags, bcnt);
        k_feat1  <<<grdN, blk, 0, stream>>>(x, W1, a1s, a1d, flags, fb_h, fb_as, fb_ad);
        k_selfinit<<<grdO, blk, 0, stream>>>(fb_as, fb_ad, fb_h, fb_den, fb_acc);
        k_edge   <<<grdE, blk, 0, stream>>>(ei, flags, fb_as, fb_ad, fb_h, fb_den, fb_acc);
        k_div_elu<<<grdO, blk, 0, stream>>>(fb_acc, fb_den, b1, flags);
        k_mid    <<<grdN, blk, 0, stream>>>(fb_acc, W2, a2s, a2d, flags, fb_h, fb_as, fb_ad);
        k_selfinit<<<grdO, blk, 0, stream>>>(fb_as, fb_ad, fb_h, fb_den, fb_acc);
        k_edge   <<<grdE, blk, 0, stream>>>(ei, flags, fb_as, fb_ad, fb_h, fb_den, fb_acc);
        k_out    <<<grdO, blk, 0, stream>>>(fb_acc, fb_den, b2, flags, out);
    } else {
        k_diag<<<grdO, blk, 0, stream>>>(out, (float)(ws_size >> 10));
    }
}